// Round 8
// baseline (239.351 us; speedup 1.0000x reference)
//
#include <hip/hip_runtime.h>
#include <math.h>

// x[32,4096,32] f32, codebook[256,32] f32
// outputs (concat f32): o_idx[N], o_probs[N*256], o_quants[N*32], o_loss[N]
//
// Structure (r8): MFMA. logits = 2*X*C^T - ||c||^2 is a GEMM -> matrix pipe
// (idle in ALL previous rounds, MfmaUtil 0.0). One wave = 16 x-rows x 256
// codes = 16 tiles of mfma_f32_16x16x32_f16. Codebook resident as f16
// hi/lo fragments (128 VGPR), loaded once per wave. Accuracy: scaled 2-term
// f16 split, 4 MFMA/tile into H/M/L partials combined in f32:
//   dot = accH + 2^-12*accM + 2^-24*accL,  residual ~2^-22*|x||c| (~1e-5
// on logits, same order as the passing f32 variants). The x4096 scaling of
// lo-terms keeps them f16-normal (no denormal-flush risk); f16 products are
// exact in f32. ||c||^2 exact-f32, seeded into the MFMA C operand.
// D layout (verified, m89): col = lane&15 (code), row = 4*(lane>>4)+reg ->
// per-row softmax reduces over 16 codes/lane x 16 lanes of ONE group ->
// within-16-lane DPP row_ror reductions. Zero LDS, zero barriers.
// A/B frag layout (m91/m92-verified convention): lane reads 8 contiguous
// k at k = 8*(lane>>4), row/col = lane&15, from row-major [.][32] arrays.
constexpr int D   = 32;
constexpr int K   = 256;
constexpr int BR  = 16;    // rows per MFMA batch (M)
constexpr int BPW = 2;     // batches per wave
constexpr int WPB = 4;     // waves per block

typedef _Float16 half8 __attribute__((ext_vector_type(8)));
typedef float    f32x4 __attribute__((ext_vector_type(4)));

template <int CTRL>
__device__ __forceinline__ int dpp_full(int v) {
    return __builtin_amdgcn_update_dpp(0, v, CTRL, 0xF, 0xF, false);
}
// within-16-lane reductions via row_ror rotate-combine; result replicated
// to all 16 lanes of each group (DPP "row" = 16 lanes on CDNA).
__device__ __forceinline__ float rmax16(float v) {
    v = fmaxf(v, __int_as_float(dpp_full<0x121>(__float_as_int(v))));  // ror:1
    v = fmaxf(v, __int_as_float(dpp_full<0x122>(__float_as_int(v))));  // ror:2
    v = fmaxf(v, __int_as_float(dpp_full<0x124>(__float_as_int(v))));  // ror:4
    v = fmaxf(v, __int_as_float(dpp_full<0x128>(__float_as_int(v))));  // ror:8
    return v;
}
__device__ __forceinline__ float radd16(float v) {
    v += __int_as_float(dpp_full<0x121>(__float_as_int(v)));
    v += __int_as_float(dpp_full<0x122>(__float_as_int(v)));
    v += __int_as_float(dpp_full<0x124>(__float_as_int(v)));
    v += __int_as_float(dpp_full<0x128>(__float_as_int(v)));
    return v;
}
__device__ __forceinline__ unsigned rmin16u(unsigned v) {
    unsigned f;
    f = (unsigned)dpp_full<0x121>((int)v); v = v < f ? v : f;
    f = (unsigned)dpp_full<0x122>((int)v); v = v < f ? v : f;
    f = (unsigned)dpp_full<0x124>((int)v); v = v < f ? v : f;
    f = (unsigned)dpp_full<0x128>((int)v); v = v < f ? v : f;
    return v;
}

__global__ __launch_bounds__(256, 2) void vq_kernel(
    const float* __restrict__ x,
    const float* __restrict__ cb,
    float* __restrict__ o_idx,
    float* __restrict__ o_probs,
    float* __restrict__ o_quants,
    float* __restrict__ o_loss)
{
    const int tid  = threadIdx.x;
    const int l    = tid & 63;
    const int wu   = __builtin_amdgcn_readfirstlane(tid >> 6);
    const int col  = l & 15;      // A: x-row within batch; B: code within tile
    const int qk   = l >> 4;      // k-quarter: k = 8*qk .. 8*qk+7
    const int wgid = blockIdx.x * WPB + wu;

    constexpr float TSC   = 2.8853900817779268f;    // 2*log2(e)
    constexpr float LN2   = 0.6931471805599453f;
    constexpr float SPLIT = 4096.0f;                // 2^12 lo-term scale
    constexpr float IM    = 0.000244140625f;        // 2^-12
    constexpr float IL    = 5.9604644775390625e-8f; // 2^-24

    // ---- init: codebook B-fragments (f16 hi + scaled lo) + -||c||^2/2 ----
    half8 bh[16], bl[16];
    float cnh[16];   // -0.5*||c||^2 for this lane's code (tile t, code t*16+col)
    #pragma unroll
    for (int t = 0; t < 16; ++t) {
        const float4* cp = reinterpret_cast<const float4*>(
            cb + (size_t)(t * 16 + col) * D + qk * 8);
        float4 c0 = cp[0], c1 = cp[1];
        float v[8] = {c0.x, c0.y, c0.z, c0.w, c1.x, c1.y, c1.z, c1.w};
        float ps = 0.f;
        #pragma unroll
        for (int e = 0; e < 8; ++e) ps = fmaf(v[e], v[e], ps);
        ps += __shfl_xor(ps, 16);   // combine the 4 k-quarters of this code
        ps += __shfl_xor(ps, 32);
        cnh[t] = -0.5f * ps;
        #pragma unroll
        for (int e = 0; e < 8; ++e) {
            _Float16 h = (_Float16)v[e];
            bh[t][e] = h;
            bl[t][e] = (_Float16)((v[e] - (float)h) * SPLIT);
        }
    }

    for (int b = 0; b < BPW; ++b) {
        const int rb = (wgid * BPW + b) * BR;

        // ---- A load: lane -> row=col, k=8*qk..+7 (two dense dwordx4) ----
        const float4* xv = reinterpret_cast<const float4*>(
            x + (size_t)(rb + col) * D + qk * 8);
        float4 a0 = xv[0], a1 = xv[1];
        float ax[8] = {a0.x, a0.y, a0.z, a0.w, a1.x, a1.y, a1.z, a1.w};

        // per-row ||x||^2 (loss only); all 4 quarter-lanes of row 'col' combine
        float xn;
        {
            float ps = 0.f;
            #pragma unroll
            for (int e = 0; e < 8; ++e) ps = fmaf(ax[e], ax[e], ps);
            ps += __shfl_xor(ps, 16);
            ps += __shfl_xor(ps, 32);
            xn = ps;
        }
        half8 ah, al;
        #pragma unroll
        for (int e = 0; e < 8; ++e) {
            _Float16 h = (_Float16)ax[e];
            ah[e] = h;
            al[e] = (_Float16)((ax[e] - (float)h) * SPLIT);
        }

        // ---- 16 tiles x 4 MFMA; combine partials in f32 ----
        // slg[t][j] = log2e * (2*dot - cn)   (the +xn shift cancels later)
        f32x4 slg[16];
        #pragma unroll
        for (int t = 0; t < 16; ++t) {
            f32x4 ch = {cnh[t], cnh[t], cnh[t], cnh[t]};
            f32x4 z  = {0.f, 0.f, 0.f, 0.f};
            f32x4 aH = __builtin_amdgcn_mfma_f32_16x16x32_f16(ah, bh[t], ch, 0, 0, 0);
            f32x4 aM = __builtin_amdgcn_mfma_f32_16x16x32_f16(ah, bl[t], z,  0, 0, 0);
            aM       = __builtin_amdgcn_mfma_f32_16x16x32_f16(al, bh[t], aM, 0, 0, 0);
            f32x4 aL = __builtin_amdgcn_mfma_f32_16x16x32_f16(al, bl[t], z,  0, 0, 0);
            f32x4 d;
            #pragma unroll
            for (int j = 0; j < 4; ++j) {
                float dd = fmaf(aM[j], IM, aH[j]);
                dd       = fmaf(aL[j], IL, dd);
                d[j]     = dd * TSC;
            }
            slg[t] = d;
        }

        // ---- per-row (j) reductions within each 16-lane group ----
        float gm[4], rs[4]; unsigned gi[4];
        #pragma unroll
        for (int j = 0; j < 4; ++j) {
            float m = slg[0][j];
            #pragma unroll
            for (int t = 1; t < 16; ++t) m = fmaxf(m, slg[t][j]);
            gm[j] = rmax16(m);
        }
        #pragma unroll
        for (int j = 0; j < 4; ++j) {
            unsigned tm = 16u;   // min tile index matching the row max
            #pragma unroll
            for (int t = 0; t < 16; ++t) {
                unsigned c = (slg[t][j] == gm[j]) ? (unsigned)t : 16u;
                tm = tm < c ? tm : c;
            }
            // no-match lanes yield >=256 -> never win the min
            gi[j] = rmin16u(tm * 16u + (unsigned)col);
        }
        #pragma unroll
        for (int j = 0; j < 4; ++j) {
            float s = 0.f;
            #pragma unroll
            for (int t = 0; t < 16; ++t) {
                float e = __builtin_amdgcn_exp2f(slg[t][j] - gm[j]);
                slg[t][j] = e;
                s += e;
            }
            rs[j] = __builtin_amdgcn_rcpf(radd16(s));
        }

        // ---- probs: row rb+4*qk+j, cols t*16+col (4x64B segments/store) ----
        float* pb = o_probs + (size_t)(rb + qk * 4) * K + col;
        #pragma unroll
        for (int j = 0; j < 4; ++j) {
            #pragma unroll
            for (int t = 0; t < 16; ++t)
                __builtin_nontemporal_store(slg[t][j] * rs[j],
                                            pb + (size_t)j * K + t * 16);
        }

        // ---- quants: group g writes row 4g+j; 16 lanes x float2 = full row ----
        #pragma unroll
        for (int j = 0; j < 4; ++j) {
            unsigned code = gi[j] & 255u;
            float2 qv = *(reinterpret_cast<const float2*>(cb + (size_t)code * D) + col);
            *(reinterpret_cast<float2*>(o_quants + (size_t)(rb + qk * 4 + j) * D) + col) = qv;
        }

        // ---- idx & loss: route row r's (gi, gm) to lane r (<16) ----
        // src lane for dst lane r = 16*(r>>2) + (r&3); that lane selects its
        // own reg index (l&3) first, then one bpermute moves it.
        const int sel = l & 3;
        unsigned ugi = gi[0]; float ugm = gm[0];
        ugi = sel == 1 ? gi[1] : ugi; ugm = sel == 1 ? gm[1] : ugm;
        ugi = sel == 2 ? gi[2] : ugi; ugm = sel == 2 ? gm[2] : ugm;
        ugi = sel == 3 ? gi[3] : ugi; ugm = sel == 3 ? gm[3] : ugm;
        const int saddr = ((((l >> 2) << 4) + sel) << 2);
        unsigned gir = (unsigned)__builtin_amdgcn_ds_bpermute(saddr, (int)ugi);
        float    gmr = __int_as_float(
            __builtin_amdgcn_ds_bpermute(saddr, __float_as_int(ugm)));
        if (l < 16) {
            o_idx [rb + l] = (float)(gir & 255u);
            // loss = 1.25 * d2min / 32; d2min = xn - gm*ln2/2 * 2 ... gm is
            // log2e*(2dot-cn): true max(2dot-cn) = gmr*ln2; d2min = xn - that.
            o_loss[rb + l] = (xn - gmr * LN2) * 0.0390625f;
        }
    }
}

extern "C" void kernel_launch(void* const* d_in, const int* in_sizes, int n_in,
                              void* d_out, int out_size, void* d_ws, size_t ws_size,
                              hipStream_t stream) {
    const float* x  = (const float*)d_in[0];
    const float* cb = (const float*)d_in[1];
    const int N = in_sizes[0] / D;   // 131072

    float* out      = (float*)d_out;
    float* o_idx    = out;
    float* o_probs  = o_idx + N;
    float* o_quants = o_probs + (size_t)N * K;
    float* o_loss   = o_quants + (size_t)N * D;

    const int grid = N / (BR * BPW * WPB);   // 1024 blocks of 256 threads
    vq_kernel<<<grid, 256, 0, stream>>>(x, cb, o_idx, o_probs, o_quants, o_loss);
}